// Round 3
// baseline (1480.828 us; speedup 1.0000x reference)
//
#include <hip/hip_runtime.h>
#include <hip/hip_bf16.h>
#include <cstdint>

typedef __bf16 bf16_t;
typedef __bf16 bf16x8 __attribute__((ext_vector_type(8)));
typedef float  f32x4  __attribute__((ext_vector_type(4)));

#define N_PTS   16384
#define C_DIM   256
#define K_NN    35
#define RSQRT32 0.17677669529663687f

// ---------------------------------------------------------------------------
// Weight transpose + fp32->bf16 convert: Wt[n][k] = W[k][n]
// ---------------------------------------------------------------------------
__global__ void convert_w_kernel(const float* __restrict__ Wq,
                                 const float* __restrict__ Wq1,
                                 const float* __restrict__ Wk,
                                 const float* __restrict__ Wv,
                                 const float* __restrict__ Wp,
                                 bf16_t* __restrict__ Wt_all) {
    int i = blockIdx.x * blockDim.x + threadIdx.x;   // 0..65535
    int which = blockIdx.y;
    const float* W = (which == 0) ? Wq : (which == 1) ? Wq1 :
                     (which == 2) ? Wk : (which == 3) ? Wv : Wp;
    int n = i >> 8, k = i & 255;
    Wt_all[(size_t)which * 65536 + i] = (bf16_t)W[k * 256 + n];
}

// ---------------------------------------------------------------------------
// Projection GEMM: out[M][256] = bf16( A_f32[M][256] @ W + bias )
// Bt is [256 n][256 k] (transposed weights, bf16). BM=128, BN=256, BK=32.
// 256 threads = 4 waves; wave w owns cols [w*64, w*64+64), all 128 rows.
// Fragment layout (verified m89/m91): A-frag lane l elem j = A[l&15][(l>>4)*8+j];
// B-frag lane l elem j = B[(l>>4)*8+j][l&15] = Bt[l&15][(l>>4)*8+j];
// C/D lane l reg r = D[(l>>4)*4+r][l&15].
// ---------------------------------------------------------------------------
__global__ __launch_bounds__(256, 2)
void proj_gemm_kernel(const float* __restrict__ A,
                      const bf16_t* __restrict__ Bt,
                      const float* __restrict__ bias,
                      bf16_t* __restrict__ out) {
    __shared__ bf16_t As[128][32];
    __shared__ bf16_t Bs[256][32];
    const int tid = threadIdx.x;
    const int w = tid >> 6, l = tid & 63;
    const int lw = l & 15, lh = l >> 4;
    const int m0 = blockIdx.x * 128;

    f32x4 acc[8][4];
#pragma unroll
    for (int m = 0; m < 8; ++m)
#pragma unroll
        for (int nn = 0; nn < 4; ++nn) acc[m][nn] = (f32x4){0.f, 0.f, 0.f, 0.f};

    const int ar = tid >> 1;          // A row this thread stages
    const int ah = (tid & 1) * 16;    // k-offset (halves of 32)

    for (int kt = 0; kt < 8; ++kt) {
        // stage A: fp32 -> bf16
        {
            const float4* ap = (const float4*)(A + (size_t)(m0 + ar) * 256 + kt * 32 + ah);
            float4 f0 = ap[0], f1 = ap[1], f2 = ap[2], f3 = ap[3];
            bf16x8 w0, w1;
            w0[0] = (bf16_t)f0.x; w0[1] = (bf16_t)f0.y; w0[2] = (bf16_t)f0.z; w0[3] = (bf16_t)f0.w;
            w0[4] = (bf16_t)f1.x; w0[5] = (bf16_t)f1.y; w0[6] = (bf16_t)f1.z; w0[7] = (bf16_t)f1.w;
            w1[0] = (bf16_t)f2.x; w1[1] = (bf16_t)f2.y; w1[2] = (bf16_t)f2.z; w1[3] = (bf16_t)f2.w;
            w1[4] = (bf16_t)f3.x; w1[5] = (bf16_t)f3.y; w1[6] = (bf16_t)f3.z; w1[7] = (bf16_t)f3.w;
            *(bf16x8*)&As[ar][ah]     = w0;
            *(bf16x8*)&As[ar][ah + 8] = w1;
        }
        // stage B: bf16 row copy (row = n)
        {
            const uint4* bp4 = (const uint4*)(Bt + (size_t)tid * 256 + kt * 32);
            uint4 b0 = bp4[0], b1 = bp4[1], b2 = bp4[2], b3 = bp4[3];
            uint4* bs4 = (uint4*)&Bs[tid][0];
            bs4[0] = b0; bs4[1] = b1; bs4[2] = b2; bs4[3] = b3;
        }
        __syncthreads();
        bf16x8 af[8], bfr[4];
#pragma unroll
        for (int m = 0; m < 8; ++m)  af[m]  = *(const bf16x8*)&As[m * 16 + lw][lh * 8];
#pragma unroll
        for (int nn = 0; nn < 4; ++nn) bfr[nn] = *(const bf16x8*)&Bs[w * 64 + nn * 16 + lw][lh * 8];
#pragma unroll
        for (int m = 0; m < 8; ++m)
#pragma unroll
            for (int nn = 0; nn < 4; ++nn)
                acc[m][nn] = __builtin_amdgcn_mfma_f32_16x16x32_bf16(af[m], bfr[nn], acc[m][nn], 0, 0, 0);
        __syncthreads();
    }
    // epilogue: bias + bf16 store
#pragma unroll
    for (int nn = 0; nn < 4; ++nn) {
        int col = w * 64 + nn * 16 + lw;
        float bc = bias[col];
#pragma unroll
        for (int m = 0; m < 8; ++m) {
            int rowb = m0 + m * 16 + lh * 4;
#pragma unroll
            for (int ri = 0; ri < 4; ++ri)
                out[(size_t)(rowb + ri) * 256 + col] = (bf16_t)(acc[m][nn][ri] + bc);
        }
    }
}

// ---------------------------------------------------------------------------
// Fused p-GEMM + attention. One block (256 thr = 4 waves) per point n.
// P[35][256] = rpe[n] @ Wp + bp computed by MFMA into LDS (rows padded to 48,
// pad rows hold garbage and are never read). Then per wave: heads 2w, 2w+1.
// ---------------------------------------------------------------------------
__device__ inline float dot8(bf16x8 a, bf16x8 b) {
    float s = 0.f;
#pragma unroll
    for (int i = 0; i < 8; ++i) s += (float)a[i] * (float)b[i];
    return s;
}

__global__ __launch_bounds__(256, 3)
void p_attn_kernel(const float* __restrict__ rpe,     // [16384*35][256] fp32
                   const bf16_t* __restrict__ Wtp,    // [256 n][256 k]
                   const float* __restrict__ bp,
                   const bf16_t* __restrict__ q_bf,
                   const bf16_t* __restrict__ q1_bf,
                   const bf16_t* __restrict__ kall,
                   const bf16_t* __restrict__ vall,
                   const int* __restrict__ knn_idx,
                   float* __restrict__ out_hidden,    // [16384][256]
                   float* __restrict__ out_probs) {   // [16384][8][35]
    __shared__ bf16_t As[48][32];
    __shared__ bf16_t Bs[256][32];
    __shared__ bf16_t Ps[48][264];   // +8 pad: row stride 528B -> 4-way max conflict
    const int n = blockIdx.x;
    const int tid = threadIdx.x;
    const int w = tid >> 6, l = tid & 63;
    const int lw = l & 15, lh = l >> 4;

    f32x4 acc[3][4];
#pragma unroll
    for (int m = 0; m < 3; ++m)
#pragma unroll
        for (int nn = 0; nn < 4; ++nn) acc[m][nn] = (f32x4){0.f, 0.f, 0.f, 0.f};

    const int ar = tid >> 1;
    const int ah = (tid & 1) * 16;

    for (int kt = 0; kt < 8; ++kt) {
        if (tid < 70) {   // stage A: 35 rows of rpe, fp32 -> bf16
            const float4* ap = (const float4*)(rpe + ((size_t)n * 35 + ar) * 256 + kt * 32 + ah);
            float4 f0 = ap[0], f1 = ap[1], f2 = ap[2], f3 = ap[3];
            bf16x8 w0, w1;
            w0[0] = (bf16_t)f0.x; w0[1] = (bf16_t)f0.y; w0[2] = (bf16_t)f0.z; w0[3] = (bf16_t)f0.w;
            w0[4] = (bf16_t)f1.x; w0[5] = (bf16_t)f1.y; w0[6] = (bf16_t)f1.z; w0[7] = (bf16_t)f1.w;
            w1[0] = (bf16_t)f2.x; w1[1] = (bf16_t)f2.y; w1[2] = (bf16_t)f2.z; w1[3] = (bf16_t)f2.w;
            w1[4] = (bf16_t)f3.x; w1[5] = (bf16_t)f3.y; w1[6] = (bf16_t)f3.z; w1[7] = (bf16_t)f3.w;
            *(bf16x8*)&As[ar][ah]     = w0;
            *(bf16x8*)&As[ar][ah + 8] = w1;
        }
        {   // stage B (Wp^T)
            const uint4* bp4 = (const uint4*)(Wtp + (size_t)tid * 256 + kt * 32);
            uint4 b0 = bp4[0], b1 = bp4[1], b2 = bp4[2], b3 = bp4[3];
            uint4* bs4 = (uint4*)&Bs[tid][0];
            bs4[0] = b0; bs4[1] = b1; bs4[2] = b2; bs4[3] = b3;
        }
        __syncthreads();
        bf16x8 af[3], bfr[4];
#pragma unroll
        for (int m = 0; m < 3; ++m)  af[m]  = *(const bf16x8*)&As[m * 16 + lw][lh * 8];
#pragma unroll
        for (int nn = 0; nn < 4; ++nn) bfr[nn] = *(const bf16x8*)&Bs[w * 64 + nn * 16 + lw][lh * 8];
#pragma unroll
        for (int m = 0; m < 3; ++m)
#pragma unroll
            for (int nn = 0; nn < 4; ++nn)
                acc[m][nn] = __builtin_amdgcn_mfma_f32_16x16x32_bf16(af[m], bfr[nn], acc[m][nn], 0, 0, 0);
        __syncthreads();
    }
    // write P (+bias) to LDS as bf16
#pragma unroll
    for (int nn = 0; nn < 4; ++nn) {
        int col = w * 64 + nn * 16 + lw;
        float bc = bp[col];
#pragma unroll
        for (int m = 0; m < 3; ++m) {
            int rowb = m * 16 + lh * 4;
#pragma unroll
            for (int ri = 0; ri < 4; ++ri)
                Ps[rowb + ri][col] = (bf16_t)(acc[m][nn][ri] + bc);
        }
    }
    __syncthreads();

    // ---------------- attention: wave w handles heads 2w, 2w+1 --------------
    const int hh = l >> 5, j = l & 31;
    const int h = w * 2 + hh;
    const int* idx = knn_idx + n * 35;
    int i1 = idx[j];
    int i2 = (j < 3) ? idx[j + 32] : 0;

    bf16x8 qv[4], q1v[4];
    {
        const bf16x8* qp  = (const bf16x8*)(q_bf  + (size_t)n * 256 + h * 32);
        const bf16x8* q1p = (const bf16x8*)(q1_bf + (size_t)n * 256 + h * 32);
#pragma unroll
        for (int c = 0; c < 4; ++c) { qv[c] = qp[c]; q1v[c] = q1p[c]; }
    }

    float s1;
    {
        const bf16x8* kp = (const bf16x8*)(kall + (size_t)i1 * 256 + h * 32);
        const bf16x8* pp = (const bf16x8*)&Ps[j][h * 32];
        float de = 0.f, dp = 0.f;
#pragma unroll
        for (int c = 0; c < 4; ++c) { de += dot8(qv[c], kp[c]); dp += dot8(q1v[c], pp[c]); }
        s1 = (de + dp) * RSQRT32;
    }
    float s2 = -1e30f;
    if (j < 3) {
        const bf16x8* kp = (const bf16x8*)(kall + (size_t)i2 * 256 + h * 32);
        const bf16x8* pp = (const bf16x8*)&Ps[j + 32][h * 32];
        float de = 0.f, dp = 0.f;
#pragma unroll
        for (int c = 0; c < 4; ++c) { de += dot8(qv[c], kp[c]); dp += dot8(q1v[c], pp[c]); }
        s2 = (de + dp) * RSQRT32;
    }

    // softmax over the 35 scores held by this 32-lane group
    float smax = fmaxf(s1, s2);
#pragma unroll
    for (int m = 1; m <= 16; m <<= 1) smax = fmaxf(smax, __shfl_xor(smax, m));
    float e1 = __expf(s1 - smax);
    float e2 = (j < 3) ? __expf(s2 - smax) : 0.f;
    float ssum = e1 + e2;
#pragma unroll
    for (int m = 1; m <= 16; m <<= 1) ssum += __shfl_xor(ssum, m);
    float inv = 1.f / ssum;
    float p1 = e1 * inv, p2 = e2 * inv;

    out_probs[(size_t)n * 280 + h * 35 + j] = p1;
    if (j < 3) out_probs[(size_t)n * 280 + h * 35 + j + 32] = p2;

    // hidden[h][d=j] = sum_k probs[k] * v_all[idx[k]][h*32+j]
    float hacc = 0.f;
    for (int k = 0; k < 35; ++k) {
        int src = hh * 32 + ((k < 32) ? k : k - 32);
        float pk = (k < 32) ? __shfl(p1, src) : __shfl(p2, src);
        int ik   = (k < 32) ? __shfl(i1, src) : __shfl(i2, src);
        hacc += pk * (float)vall[(size_t)ik * 256 + h * 32 + j];
    }
    out_hidden[(size_t)n * 256 + h * 32 + j] = hacc;
}

// ---------------------------------------------------------------------------
extern "C" void kernel_launch(void* const* d_in, const int* in_sizes, int n_in,
                              void* d_out, int out_size, void* d_ws, size_t ws_size,
                              hipStream_t stream) {
    const float* input_q = (const float*)d_in[0];
    const float* input_k = (const float*)d_in[1];
    const float* input_v = (const float*)d_in[2];
    const float* rpe     = (const float*)d_in[3];
    const int*   knn_idx = (const int*)d_in[4];
    const float* Wq  = (const float*)d_in[5];
    const float* bq  = (const float*)d_in[6];
    const float* Wq1 = (const float*)d_in[7];
    const float* bq1 = (const float*)d_in[8];
    const float* Wk  = (const float*)d_in[9];
    const float* bk  = (const float*)d_in[10];
    const float* Wv  = (const float*)d_in[11];
    const float* bv  = (const float*)d_in[12];
    const float* Wp  = (const float*)d_in[13];
    const float* bp  = (const float*)d_in[14];

    char* ws = (char*)d_ws;
    bf16_t* Wt_all = (bf16_t*)ws;                     // 5 * 65536 bf16
    bf16_t* q_bf   = (bf16_t*)(ws + 655360);
    bf16_t* q1_bf  = q_bf  + 4194304;
    bf16_t* kall   = q1_bf + 4194304;
    bf16_t* vall   = kall  + 4194304;

    float* out_hidden = (float*)d_out;
    float* out_probs  = out_hidden + (size_t)N_PTS * C_DIM;

    convert_w_kernel<<<dim3(256, 5), 256, 0, stream>>>(Wq, Wq1, Wk, Wv, Wp, Wt_all);
    proj_gemm_kernel<<<128, 256, 0, stream>>>(input_q, Wt_all,           bq,  q_bf);
    proj_gemm_kernel<<<128, 256, 0, stream>>>(input_q, Wt_all + 65536,   bq1, q1_bf);
    proj_gemm_kernel<<<128, 256, 0, stream>>>(input_k, Wt_all + 131072,  bk,  kall);
    proj_gemm_kernel<<<128, 256, 0, stream>>>(input_v, Wt_all + 196608,  bv,  vall);
    p_attn_kernel<<<N_PTS, 256, 0, stream>>>(rpe, Wt_all + 262144, bp,
                                             q_bf, q1_bf, kall, vall, knn_idx,
                                             out_hidden, out_probs);
}